// Round 6
// baseline (564.578 us; speedup 1.0000x reference)
//
#include <hip/hip_runtime.h>
#include <cstdint>

typedef unsigned short u16;
typedef u16 u16x8 __attribute__((ext_vector_type(8)));
typedef __bf16 bf16x8 __attribute__((ext_vector_type(8)));
typedef float f32x4 __attribute__((ext_vector_type(4)));

#define GLOAD_LDS16(g, l)                                                          \
  __builtin_amdgcn_global_load_lds((const __attribute__((address_space(1))) void*)(g), \
                                   (__attribute__((address_space(3))) void*)(l), 16, 0, 0)

#define BARRIER() do { asm volatile("" ::: "memory");                 \
                       __builtin_amdgcn_sched_barrier(0);             \
                       __builtin_amdgcn_s_barrier();                  \
                       __builtin_amdgcn_sched_barrier(0);             \
                       asm volatile("" ::: "memory"); } while (0)
#define VMCNT4() asm volatile("s_waitcnt vmcnt(4)" ::: "memory")
#define VMCNT0() asm volatile("s_waitcnt vmcnt(0)" ::: "memory")

__device__ __forceinline__ u16 f2bf(float f) {
  union { float f; uint32_t u; } v; v.f = f;
  uint32_t u = v.u;
  return (u16)((u + 0x7fffu + ((u >> 16) & 1u)) >> 16);  // RNE
}

constexpr long MH = 67108864L;    // 16384*4096
constexpr long MV = 8388608L;     // 2048*4096
constexpr long MU = 262144L;      // 32*128*64

// ---------------- single f32 -> bf16 pass over {H, VT, U} (contiguous dst) ----------------
__global__ __launch_bounds__(256) void cvt_all(const float* __restrict__ H,
                                               const float* __restrict__ VT,
                                               const float* __restrict__ Uw,
                                               u16* __restrict__ dst) {
  const long n8 = (MH + MV + MU) / 8;
  long i = (long)blockIdx.x * blockDim.x + threadIdx.x;
  long stride = (long)gridDim.x * blockDim.x;
  for (; i < n8; i += stride) {
    long j = i * 8;
    const float* src;
    if (j < MH)            src = H + j;
    else if (j < MH + MV)  src = VT + (j - MH);
    else                   src = Uw + (j - MH - MV);
    const float4* p = (const float4*)src;
    float4 a = p[0], b = p[1];
    u16x8 o;
    o[0] = f2bf(a.x); o[1] = f2bf(a.y); o[2] = f2bf(a.z); o[3] = f2bf(a.w);
    o[4] = f2bf(b.x); o[5] = f2bf(b.y); o[6] = f2bf(b.z); o[7] = f2bf(b.w);
    *(u16x8*)(dst + j) = o;
  }
}

// ============ Fused: latents = H @ VT^T (256x256, BK=64, 8-phase, read-ahead-1) + U proj ============
constexpr int GK = 4096;
constexpr int NKT = GK / 64;   // 64 K-tiles

__device__ __forceinline__ void stage_half(u16* sm, const u16* g, int ldsbase, int w) {
  u16* l0 = sm + ldsbase + w * 1024;
  GLOAD_LDS16(g, l0);
  GLOAD_LDS16(g + 8 * GK, l0 + 512);
}

__device__ __forceinline__ void readA(const u16* sm, int base, int msub, bf16x8* fA) {
#pragma unroll
  for (int mf = 0; mf < 4; ++mf) {
    int idx = base + (msub * 64 + mf * 16) * 64;
    fA[mf * 2]     = *(const bf16x8*)(sm + idx);
    fA[mf * 2 + 1] = *(const bf16x8*)(sm + (idx ^ 32));   // ks=1: k-slot +4 (XOR bit5)
  }
}

__device__ __forceinline__ void readB(const u16* sm, int base, int qn, bf16x8* fB) {
#pragma unroll
  for (int nf = 0; nf < 2; ++nf) {
    int idx = base + (qn * 32 + nf * 16) * 64;
    fB[nf * 2]     = *(const bf16x8*)(sm + idx);
    fB[nf * 2 + 1] = *(const bf16x8*)(sm + (idx ^ 32));
  }
}

__device__ __forceinline__ void mfma8(const bf16x8* fA, const bf16x8* fB,
                                      f32x4 (*acc)[4], int mbase, int nbase) {
  __builtin_amdgcn_s_setprio(1);
#pragma unroll
  for (int mf = 0; mf < 4; ++mf)
#pragma unroll
    for (int nf = 0; nf < 2; ++nf) {
      acc[mbase + mf][nbase + nf] = __builtin_amdgcn_mfma_f32_16x16x32_bf16(
          fA[mf * 2], fB[nf * 2], acc[mbase + mf][nbase + nf], 0, 0, 0);
      acc[mbase + mf][nbase + nf] = __builtin_amdgcn_mfma_f32_16x16x32_bf16(
          fA[mf * 2 + 1], fB[nf * 2 + 1], acc[mbase + mf][nbase + nf], 0, 0, 0);
    }
  __builtin_amdgcn_s_setprio(0);
}

// One iteration = 2 K-tiles (2i -> buf0 "e", 2i+1 -> buf1 "o"), 8 phases.
// Reads shifted one phase ahead of their first MFMA use; stage/vmcnt ledger
// identical to R4 (audited: read-ahead only shortens LDS buffer lifetimes).
// Frag lifetimes: fA0e ph8->ph2, fA1e ph2->ph4, fA0o ph4->ph6, fA1o ph6->ph8,
//                 fB0e ph8->ph4, fB1e ph1->ph3, fB0o ph4->ph8, fB1o ph5->ph7.
template <bool MORE>
__device__ __forceinline__ void kiter(u16* sm, int i, int w,
                                      const u16* gAs, const u16* gBs,
                                      int Ab0, int Bb0,
                                      bf16x8* fA0e, bf16x8* fA1e,
                                      bf16x8* fA0o, bf16x8* fA1o,
                                      bf16x8* fB0e, bf16x8* fB1e,
                                      bf16x8* fB0o, bf16x8* fB1o,
                                      f32x4 (*acc)[4]) {
  const long dOdd = (long)(2 * i + 1) * 64;
  const long dE2  = (long)(2 * i + 2) * 64;
  const long dO3  = (long)(2 * i + 3) * 64;
  const long hOff = 128L * GK;

  // ph1: read B-n1(e) [q2 operand]; stage B1(2i+1)->buf1; MFMA q(m0,n0) e
  readB(sm, Bb0, 1, fB1e);
  stage_half(sm, gBs + hOff + dOdd, 32768 + 24576, w);
  BARRIER();
  mfma8(fA0e, fB0e, acc, 0, 0);
  BARRIER();
  // ph2: read A-m1(e) [q3]; stage A1(2i+1)->buf1; MFMA q(m0,n1) e
  readA(sm, Ab0, 1, fA1e);
  stage_half(sm, gAs + hOff + dOdd, 24576, w);
  BARRIER();
  mfma8(fA0e, fB1e, acc, 0, 2);
  BARRIER();
  // ph3: stage B0(2i+2)->buf0 (B(e) dead since ph1's read); MFMA q(m1,n1) e
  if constexpr (MORE) stage_half(sm, gBs + dE2, 32768, w);
  BARRIER();
  mfma8(fA1e, fB1e, acc, 4, 2);
  BARRIER();
  // ph4: stage A0(2i+2)->buf0 (A(e) dead since ph2); counted vmcnt -> tile 2i+1
  //      landed; read next tile's first operands (buf1); MFMA q(m1,n0) e
  if constexpr (MORE) stage_half(sm, gAs + dE2, 0, w);
  if constexpr (MORE) VMCNT4(); else VMCNT0();
  BARRIER();
  readA(sm, Ab0 + 16384, 0, fA0o);
  readB(sm, Bb0 + 16384, 0, fB0o);
  mfma8(fA1e, fB0e, acc, 4, 0);
  BARRIER();
  // ph5: read B-n1(o); stage B1(2i+2)->buf0; MFMA q(m0,n0) o
  readB(sm, Bb0 + 16384, 1, fB1o);
  if constexpr (MORE) stage_half(sm, gBs + hOff + dE2, 32768 + 8192, w);
  BARRIER();
  mfma8(fA0o, fB0o, acc, 0, 0);
  BARRIER();
  // ph6: read A-m1(o); stage A1(2i+2)->buf0; MFMA q(m0,n1) o
  readA(sm, Ab0 + 16384, 1, fA1o);
  if constexpr (MORE) stage_half(sm, gAs + hOff + dE2, 8192, w);
  BARRIER();
  mfma8(fA0o, fB1o, acc, 0, 2);
  BARRIER();
  // ph7: stage B0(2i+3)->buf1 (B(o) dead since ph5); MFMA q(m1,n1) o
  if constexpr (MORE) stage_half(sm, gBs + dO3, 32768 + 16384, w);
  BARRIER();
  mfma8(fA1o, fB1o, acc, 4, 2);
  BARRIER();
  // ph8: stage A0(2i+3)->buf1 (A(o) dead since ph6); counted vmcnt -> tile 2i+2
  //      landed (B0 ph3 / A0 ph4 / B1 ph5 / A1 ph6); read its first operands;
  //      MFMA q(m1,n0) o
  if constexpr (MORE) stage_half(sm, gAs + dO3, 16384, w);
  if constexpr (MORE) VMCNT4(); else VMCNT0();
  BARRIER();
  if constexpr (MORE) {
    readA(sm, Ab0, 0, fA0e);
    readB(sm, Bb0, 0, fB0e);
  }
  mfma8(fA1o, fB0o, acc, 4, 0);
  BARRIER();
}

__global__ __launch_bounds__(512, 2) void gemm256_fused(const u16* __restrict__ A,
                                                        const u16* __restrict__ B,
                                                        const u16* __restrict__ Ubf,
                                                        const float* __restrict__ Ubias,
                                                        float* __restrict__ out) {
  // LDS: K-loop ring uses [0, 65536); epilogue lat tile [256][260] uses [0, 66560)
  __shared__ u16 sm[66560];
  int bid = blockIdx.x;               // 512 blocks, 512 % 8 == 0 -> bijective XCD swizzle
  int swz = (bid & 7) * 64 + (bid >> 3);
  int tn = swz & 7;
  int tm = swz >> 3;
  int t0 = threadIdx.x;
  int w = t0 >> 6, l = t0 & 63;
  int wr = w >> 2, wc = w & 3;        // 2 M-waves x 4 N-waves; per-wave 128x64 latents
  int lo = l & 15, hi = l >> 4;

  // staging source (pre-swizzled: LDS slot s of row r holds global k-slot s ^ (r&7))
  int lr = l >> 3;
  int sslot = (l & 7) ^ lr;
  const u16* gAs = A + (long)(tm * 256 + w * 16 + lr) * GK + sslot * 8;
  const u16* gBs = B + (long)(tn * 256 + w * 16 + lr) * GK + sslot * 8;

  // ds_read bases (u16): row-in-half = <sub>*16 + lo, 64 u16/row; slot = kslot ^ (lo&7)
  int slotbase = (hi ^ (lo & 7)) * 8;
  int Ab0 = wr * 8192 + lo * 64 + slotbase;
  int Bb0 = 32768 + (wc >> 1) * 8192 + ((wc & 1) * 64 + lo) * 64 + slotbase;

  bf16x8 fA0e[8], fA1e[8], fA0o[8], fA1o[8];
  bf16x8 fB0e[4], fB1e[4], fB0o[4], fB1o[4];
  f32x4 acc[8][4] = {};

  // prologue: tile0 all 4 halves + tile1 {B0,A0}; vmcnt(4) -> tile0 landed;
  // then pre-read tile0's first operands (ph0)
  stage_half(sm, gBs,               32768,         w);
  stage_half(sm, gAs,               0,             w);
  stage_half(sm, gBs + 128L * GK,   32768 + 8192,  w);
  stage_half(sm, gAs + 128L * GK,   8192,          w);
  stage_half(sm, gBs + 64,          32768 + 16384, w);
  stage_half(sm, gAs + 64,          16384,         w);
  VMCNT4();
  BARRIER();
  readA(sm, Ab0, 0, fA0e);
  readB(sm, Bb0, 0, fB0e);

  for (int i = 0; i < NKT / 2 - 1; ++i)
    kiter<true>(sm, i, w, gAs, gBs, Ab0, Bb0,
                fA0e, fA1e, fA0o, fA1o, fB0e, fB1e, fB0o, fB1o, acc);
  kiter<false>(sm, NKT / 2 - 1, w, gAs, gBs, Ab0, Bb0,
               fA0e, fA1e, fA0o, fA1o, fB0e, fB1e, fB0o, fB1o, acc);

  // ================= fused stage-2 epilogue (wave-local) =================
  // Wave (wr,wc) owns lat rows [wr*128,+128) x cols [wc*64,+64) = group tn*4+wc.
  int g_abs = tn * 4 + wc;
#pragma unroll
  for (int mq = 0; mq < 8; ++mq)
#pragma unroll
    for (int n = 0; n < 4; ++n) {
      int rl = wr * 128 + mq * 16 + hi * 4;
      int cl = wc * 64 + n * 16 + lo;
#pragma unroll
      for (int j = 0; j < 4; ++j)
        sm[(rl + j) * 260 + cl] = f2bf(acc[mq][n][j]);
    }
  // per-wave ds_write -> ds_read ordering enforced by compiler lgkmcnt tracking
  const u16* Ug = Ubf + g_abs * 8192;        // [128][64] bf16, K-contiguous
#pragma unroll
  for (int mh = 0; mh < 2; ++mh) {
    bf16x8 fL[8];
#pragma unroll
    for (int ms = 0; ms < 4; ++ms) {
      int rl = wr * 128 + mh * 64 + ms * 16 + lo;
#pragma unroll
      for (int ks = 0; ks < 2; ++ks)
        fL[ms * 2 + ks] = *(const bf16x8*)(sm + rl * 260 + wc * 64 + ks * 32 + hi * 8);
    }
#pragma unroll
    for (int nf = 0; nf < 8; ++nf) {
      int d = nf * 16 + lo;
      bf16x8 u0 = *(const bf16x8*)(Ug + d * 64 + hi * 8);
      bf16x8 u1 = *(const bf16x8*)(Ug + d * 64 + 32 + hi * 8);
      float bias = Ubias[g_abs * 128 + d];
#pragma unroll
      for (int ms = 0; ms < 4; ++ms) {
        f32x4 o = {};
        o = __builtin_amdgcn_mfma_f32_16x16x32_bf16(fL[ms * 2],     u0, o, 0, 0, 0);
        o = __builtin_amdgcn_mfma_f32_16x16x32_bf16(fL[ms * 2 + 1], u1, o, 0, 0, 0);
        long row = (long)tm * 256 + wr * 128 + mh * 64 + ms * 16 + hi * 4;
        int col = g_abs * 128 + d;
#pragma unroll
        for (int j = 0; j < 4; ++j)
          out[(row + j) * 4096 + col] = o[j] + bias;
      }
    }
  }
}

// ============ Fallback (small ws): 128x128 m97-style, A converted in-kernel ============
__global__ __launch_bounds__(256) void gemm1_f32(const float* __restrict__ fAp,
                                                 const u16* __restrict__ B,
                                                 u16* __restrict__ Cl) {
  constexpr int K = 4096;
  __shared__ u16 sA[128 * 32];
  __shared__ u16 sB[128 * 32];
  int bid = blockIdx.x;
  int swz = (bid & 7) * 256 + (bid >> 3);
  int tn = swz & 15;
  int tm = swz >> 4;
  int t = threadIdx.x;
  int w = t >> 6, l = t & 63;
  int wr = w >> 1, wc = w & 1;
  int lo = l & 15, hi = l >> 4;
  const int rS = w * 32 + (l >> 2);
  const int kS = (l & 3) * 8;
  const u16* gB = B + (long)(tn * 128 + rS) * K + kS;
  u16* lB = &sB[w * 1024];
  int fr = t >> 1, fk = (t & 1) * 16;

  f32x4 acc[4][4] = {};
  for (int k0 = 0; k0 < K; k0 += 32) {
    const float* src = fAp + (long)(tm * 128 + fr) * K + k0 + fk;
    float4 x = *(const float4*)(src);
    float4 y = *(const float4*)(src + 4);
    float4 z = *(const float4*)(src + 8);
    float4 q = *(const float4*)(src + 12);
    u16x8 o1, o2;
    o1[0] = f2bf(x.x); o1[1] = f2bf(x.y); o1[2] = f2bf(x.z); o1[3] = f2bf(x.w);
    o1[4] = f2bf(y.x); o1[5] = f2bf(y.y); o1[6] = f2bf(y.z); o1[7] = f2bf(y.w);
    o2[0] = f2bf(z.x); o2[1] = f2bf(z.y); o2[2] = f2bf(z.z); o2[3] = f2bf(z.w);
    o2[4] = f2bf(q.x); o2[5] = f2bf(q.y); o2[6] = f2bf(q.z); o2[7] = f2bf(q.w);
    *(u16x8*)&sA[fr * 32 + fk] = o1;
    *(u16x8*)&sA[fr * 32 + fk + 8] = o2;
    GLOAD_LDS16(gB, lB);
    GLOAD_LDS16(gB + 16 * K, lB + 512);
    gB += 32;
    __syncthreads();
    bf16x8 af[4], bfr[4];
#pragma unroll
    for (int m = 0; m < 4; ++m)
      af[m] = *(const bf16x8*)&sA[(wr * 64 + m * 16 + lo) * 32 + hi * 8];
#pragma unroll
    for (int n = 0; n < 4; ++n)
      bfr[n] = *(const bf16x8*)&sB[(wc * 64 + n * 16 + lo) * 32 + hi * 8];
#pragma unroll
    for (int m = 0; m < 4; ++m)
#pragma unroll
      for (int n = 0; n < 4; ++n)
        acc[m][n] = __builtin_amdgcn_mfma_f32_16x16x32_bf16(af[m], bfr[n], acc[m][n], 0, 0, 0);
    __syncthreads();
  }
#pragma unroll
  for (int m = 0; m < 4; ++m)
#pragma unroll
    for (int n = 0; n < 4; ++n) {
      int col = tn * 128 + wc * 64 + n * 16 + lo;
      int row = tm * 128 + wr * 64 + m * 16 + hi * 4;
#pragma unroll
      for (int j = 0; j < 4; ++j)
        Cl[(long)(row + j) * 2048 + col] = f2bf(acc[m][n][j]);
    }
}

// ---------------- Fallback stage 2 ----------------
__global__ __launch_bounds__(256) void stage2(const u16* __restrict__ L,
                                              const u16* __restrict__ U,
                                              const float* __restrict__ Ub,
                                              float* __restrict__ out) {
  int tm = blockIdx.x, g = blockIdx.y;
  int t = threadIdx.x, w = t >> 6, l = t & 63;
  int lo = l & 15, hi = l >> 4;
  const u16* Lb = L + (long)(tm * 128 + w * 32) * 2048 + g * 64;
  const u16* Ug = U + g * 8192;
  f32x4 acc[2][8] = {};
#pragma unroll
  for (int ks = 0; ks < 2; ++ks) {
    int ek = ks * 32 + hi * 8;
    bf16x8 a0 = *(const bf16x8*)(Lb + (long)lo * 2048 + ek);
    bf16x8 a1 = *(const bf16x8*)(Lb + (long)(lo + 16) * 2048 + ek);
#pragma unroll
    for (int n = 0; n < 8; ++n) {
      bf16x8 bv = *(const bf16x8*)(Ug + (n * 16 + lo) * 64 + ek);
      acc[0][n] = __builtin_amdgcn_mfma_f32_16x16x32_bf16(a0, bv, acc[0][n], 0, 0, 0);
      acc[1][n] = __builtin_amdgcn_mfma_f32_16x16x32_bf16(a1, bv, acc[1][n], 0, 0, 0);
    }
  }
#pragma unroll
  for (int n = 0; n < 8; ++n) {
    int col = n * 16 + lo;
    float bias = Ub[g * 128 + col];
#pragma unroll
    for (int m = 0; m < 2; ++m) {
      int row = tm * 128 + w * 32 + m * 16 + hi * 4;
#pragma unroll
      for (int j = 0; j < 4; ++j)
        out[(long)(row + j) * 4096 + g * 128 + col] = acc[m][n][j] + bias;
    }
  }
}

__global__ __launch_bounds__(256) void cvt_f32_bf16(const float* __restrict__ in,
                                                    u16* __restrict__ out, long n8) {
  long i = (long)blockIdx.x * blockDim.x + threadIdx.x;
  long stride = (long)gridDim.x * blockDim.x;
  for (; i < n8; i += stride) {
    const float4* p = (const float4*)(in + i * 8);
    float4 a = p[0], b = p[1];
    u16x8 o;
    o[0] = f2bf(a.x); o[1] = f2bf(a.y); o[2] = f2bf(a.z); o[3] = f2bf(a.w);
    o[4] = f2bf(b.x); o[5] = f2bf(b.y); o[6] = f2bf(b.z); o[7] = f2bf(b.w);
    *(u16x8*)(out + i * 8) = o;
  }
}

extern "C" void kernel_launch(void* const* d_in, const int* in_sizes, int n_in,
                              void* d_out, int out_size, void* d_ws, size_t ws_size,
                              hipStream_t stream) {
  const float* H   = (const float*)d_in[0];   // [4,4096,4096]
  const float* VT  = (const float*)d_in[1];   // [2048,4096]
  const float* Uw  = (const float*)d_in[2];   // [32,128,64]
  const float* Ubp = (const float*)d_in[3];   // [32,128]
  float* out = (float*)d_out;                 // [4,4096,4096]
  size_t needFull = (size_t)(MH + MV + MU) * 2;   // ~151.6 MB

  if (ws_size >= needFull) {
    u16* hbf = (u16*)d_ws;
    u16* vbf = hbf + MH;
    u16* ubf = vbf + MV;
    cvt_all<<<2048, 256, 0, stream>>>(H, VT, Uw, hbf);
    gemm256_fused<<<512, 512, 0, stream>>>(hbf, vbf, ubf, Ubp, out);
  } else {
    u16* vbf = (u16*)d_ws;
    u16* ubf = vbf + MV;
    u16* lat = ubf + MU;
    cvt_f32_bf16<<<512, 256, 0, stream>>>(VT, vbf, MV / 8);
    cvt_f32_bf16<<<128, 256, 0, stream>>>(Uw, ubf, MU / 8);
    gemm1_f32<<<2048, 256, 0, stream>>>(H, vbf, lat);
    stage2<<<dim3(128, 32), 256, 0, stream>>>(lat, ubf, Ubp, out);
  }
}

// Round 7
// 379.099 us; speedup vs baseline: 1.4893x; 1.4893x over previous
//
#include <hip/hip_runtime.h>
#include <cstdint>

typedef unsigned short u16;
typedef u16 u16x8 __attribute__((ext_vector_type(8)));
typedef __bf16 bf16x8 __attribute__((ext_vector_type(8)));
typedef float f32x4 __attribute__((ext_vector_type(4)));
typedef float f32x16 __attribute__((ext_vector_type(16)));

#define GLOAD_LDS16(g, l)                                                          \
  __builtin_amdgcn_global_load_lds((const __attribute__((address_space(1))) void*)(g), \
                                   (__attribute__((address_space(3))) void*)(l), 16, 0, 0)

#define BARRIER() do { asm volatile("" ::: "memory");                 \
                       __builtin_amdgcn_sched_barrier(0);             \
                       __builtin_amdgcn_s_barrier();                  \
                       __builtin_amdgcn_sched_barrier(0);             \
                       asm volatile("" ::: "memory"); } while (0)
#define VMCNT4() asm volatile("s_waitcnt vmcnt(4)" ::: "memory")
#define VMCNT0() asm volatile("s_waitcnt vmcnt(0)" ::: "memory")

__device__ __forceinline__ u16 f2bf(float f) {
  union { float f; uint32_t u; } v; v.f = f;
  uint32_t u = v.u;
  return (u16)((u + 0x7fffu + ((u >> 16) & 1u)) >> 16);  // RNE
}

constexpr long MH = 67108864L;    // 16384*4096
constexpr long MV = 8388608L;     // 2048*4096
constexpr long MU = 262144L;      // 32*128*64

// ---------------- single f32 -> bf16 pass over {H, VT, U} (contiguous dst) ----------------
__global__ __launch_bounds__(256) void cvt_all(const float* __restrict__ H,
                                               const float* __restrict__ VT,
                                               const float* __restrict__ Uw,
                                               u16* __restrict__ dst) {
  const long n8 = (MH + MV + MU) / 8;
  long i = (long)blockIdx.x * blockDim.x + threadIdx.x;
  long stride = (long)gridDim.x * blockDim.x;
  for (; i < n8; i += stride) {
    long j = i * 8;
    const float* src;
    if (j < MH)            src = H + j;
    else if (j < MH + MV)  src = VT + (j - MH);
    else                   src = Uw + (j - MH - MV);
    const float4* p = (const float4*)src;
    float4 a = p[0], b = p[1];
    u16x8 o;
    o[0] = f2bf(a.x); o[1] = f2bf(a.y); o[2] = f2bf(a.z); o[3] = f2bf(a.w);
    o[4] = f2bf(b.x); o[5] = f2bf(b.y); o[6] = f2bf(b.z); o[7] = f2bf(b.w);
    *(u16x8*)(dst + j) = o;
  }
}

// ============ Fused: latents = H @ VT^T (256x256, BK=64, 8-phase, 32x32x16) + U proj ============
constexpr int GK = 4096;
constexpr int NKT = GK / 64;   // 64 K-tiles

__device__ __forceinline__ void stage_half(u16* sm, const u16* g, int ldsbase, int w) {
  u16* l0 = sm + ldsbase + w * 1024;
  GLOAD_LDS16(g, l0);
  GLOAD_LDS16(g + 8 * GK, l0 + 512);
}

// 32x32x16 fragment reads. row_in_half = msub*64 + mt2*32 + l31 (A) / (wc&1)*64 + nt*32 + l31 (B)
// LDS slot s holds global k-slot s ^ (row&7); frag k-slot = ks*2 + hi5.
__device__ __forceinline__ void readA32(const u16* sm, int base, int msub,
                                        int s0, int s1, int s2, int s3, bf16x8* fA) {
#pragma unroll
  for (int mt2 = 0; mt2 < 2; ++mt2) {
    int rb = base + (msub * 64 + mt2 * 32) * 64;
    fA[mt2 * 4 + 0] = *(const bf16x8*)(sm + rb + s0);
    fA[mt2 * 4 + 1] = *(const bf16x8*)(sm + rb + s1);
    fA[mt2 * 4 + 2] = *(const bf16x8*)(sm + rb + s2);
    fA[mt2 * 4 + 3] = *(const bf16x8*)(sm + rb + s3);
  }
}

__device__ __forceinline__ void readB32(const u16* sm, int base, int nt,
                                        int s0, int s1, int s2, int s3, bf16x8* fB) {
  int rb = base + (nt * 32) * 64;
  fB[0] = *(const bf16x8*)(sm + rb + s0);
  fB[1] = *(const bf16x8*)(sm + rb + s1);
  fB[2] = *(const bf16x8*)(sm + rb + s2);
  fB[3] = *(const bf16x8*)(sm + rb + s3);
}

// 8 x mfma_32x32x16: quadrant (msub, nt), acc[4][2] of f32x16
__device__ __forceinline__ void mfma8x32(const bf16x8* fA, const bf16x8* fB,
                                         f32x16 (*acc)[2], int msub, int nt) {
  __builtin_amdgcn_s_setprio(1);
#pragma unroll
  for (int mt2 = 0; mt2 < 2; ++mt2)
#pragma unroll
    for (int ks = 0; ks < 4; ++ks)
      acc[msub * 2 + mt2][nt] = __builtin_amdgcn_mfma_f32_32x32x16_bf16(
          fA[mt2 * 4 + ks], fB[ks], acc[msub * 2 + mt2][nt], 0, 0, 0);
  __builtin_amdgcn_s_setprio(0);
}

// One iteration = 2 K-tiles (2i -> buf0, 2i+1 -> buf1), 8 phases.
// Stage ledger identical to R4/R5 (audited): ph1:B1(2i+1) ph2:A1(2i+1) ph3:B0(2i+2)
// ph4:A0(2i+2)+vmcnt4  ph5:B1(2i+2) ph6:A1(2i+2) ph7:B0(2i+3) ph8:A0(2i+3)+vmcnt4
template <bool MORE>
__device__ __forceinline__ void kiter(u16* sm, int i, int w,
                                      const u16* gAs, const u16* gBs,
                                      int Ab0, int Bb0,
                                      int s0, int s1, int s2, int s3,
                                      bf16x8* fA, bf16x8* fB0, bf16x8* fB1,
                                      f32x16 (*acc)[2]) {
  const long dOdd = (long)(2 * i + 1) * 64;
  const long dE2  = (long)(2 * i + 2) * 64;
  const long dO3  = (long)(2 * i + 3) * 64;
  const long hOff = 128L * GK;

  // ph1: read A(msub0)+B(nt0) buf0; stage B1(2i+1)->buf1; MFMA q(m0,n0)
  readA32(sm, Ab0, 0, s0, s1, s2, s3, fA);
  readB32(sm, Bb0, 0, s0, s1, s2, s3, fB0);
  stage_half(sm, gBs + hOff + dOdd, 32768 + 24576, w);
  BARRIER();
  mfma8x32(fA, fB0, acc, 0, 0);
  BARRIER();
  // ph2: read B(nt1) buf0; stage A1(2i+1)->buf1; MFMA q(m0,n1)
  readB32(sm, Bb0, 1, s0, s1, s2, s3, fB1);
  stage_half(sm, gAs + hOff + dOdd, 24576, w);
  BARRIER();
  mfma8x32(fA, fB1, acc, 0, 1);
  BARRIER();
  // ph3: read A(msub1) buf0; stage B0(2i+2)->buf0 (dead since ph2); MFMA q(m1,n1)
  readA32(sm, Ab0, 1, s0, s1, s2, s3, fA);
  if constexpr (MORE) stage_half(sm, gBs + dE2, 32768, w);
  BARRIER();
  mfma8x32(fA, fB1, acc, 1, 1);
  BARRIER();
  // ph4: stage A0(2i+2)->buf0 (dead since ph3); counted vmcnt; MFMA q(m1,n0)
  if constexpr (MORE) stage_half(sm, gAs + dE2, 0, w);
  if constexpr (MORE) VMCNT4(); else VMCNT0();
  BARRIER();
  mfma8x32(fA, fB0, acc, 1, 0);
  BARRIER();
  // ph5: read A(msub0)+B(nt0) buf1; stage B1(2i+2)->buf0; MFMA q(m0,n0)
  readA32(sm, Ab0 + 16384, 0, s0, s1, s2, s3, fA);
  readB32(sm, Bb0 + 16384, 0, s0, s1, s2, s3, fB0);
  if constexpr (MORE) stage_half(sm, gBs + hOff + dE2, 32768 + 8192, w);
  BARRIER();
  mfma8x32(fA, fB0, acc, 0, 0);
  BARRIER();
  // ph6: read B(nt1) buf1; stage A1(2i+2)->buf0; MFMA q(m0,n1)
  readB32(sm, Bb0 + 16384, 1, s0, s1, s2, s3, fB1);
  if constexpr (MORE) stage_half(sm, gAs + hOff + dE2, 8192, w);
  BARRIER();
  mfma8x32(fA, fB1, acc, 0, 1);
  BARRIER();
  // ph7: read A(msub1) buf1; stage B0(2i+3)->buf1 (dead since ph6); MFMA q(m1,n1)
  readA32(sm, Ab0 + 16384, 1, s0, s1, s2, s3, fA);
  if constexpr (MORE) stage_half(sm, gBs + dO3, 32768 + 16384, w);
  BARRIER();
  mfma8x32(fA, fB1, acc, 1, 1);
  BARRIER();
  // ph8: stage A0(2i+3)->buf1 (dead since ph7); counted vmcnt; MFMA q(m1,n0)
  if constexpr (MORE) stage_half(sm, gAs + dO3, 16384, w);
  if constexpr (MORE) VMCNT4(); else VMCNT0();
  BARRIER();
  mfma8x32(fA, fB0, acc, 1, 0);
  BARRIER();
}

__global__ __launch_bounds__(512, 2) void gemm256_fused(const u16* __restrict__ A,
                                                        const u16* __restrict__ B,
                                                        const u16* __restrict__ Ubf,
                                                        const float* __restrict__ Ubias,
                                                        float* __restrict__ out) {
  // LDS: K-loop ring uses [0, 65536); epilogue lat tile [256][260] uses [0, 66560)
  __shared__ u16 sm[66560];
  int bid = blockIdx.x;               // 512 blocks, 512 % 8 == 0 -> bijective XCD swizzle
  int swz = (bid & 7) * 64 + (bid >> 3);
  int tn = swz & 7;
  int tm = swz >> 3;
  int t0 = threadIdx.x;
  int w = t0 >> 6, l = t0 & 63;
  int wr = w >> 2, wc = w & 3;        // 2 M-waves x 4 N-waves; per-wave 128x64 latents
  int lo = l & 15, hi = l >> 4;       // 16x16 decomposition (epilogue U-proj)
  int l31 = l & 31, hi5 = l >> 5;     // 32x32 decomposition (K-loop)
  int lkey = l & 7;

  // staging source (pre-swizzled: LDS slot s of row r holds global k-slot s ^ (r&7))
  int lr = l >> 3;
  int sslot = (l & 7) ^ lr;
  const u16* gAs = A + (long)(tm * 256 + w * 16 + lr) * GK + sslot * 8;
  const u16* gBs = B + (long)(tn * 256 + w * 16 + lr) * GK + sslot * 8;

  // ds_read bases (u16 units) and the 4 swizzled k-slot offsets (ks = 0..3)
  int Ab0 = wr * 8192 + l31 * 64;
  int Bb0 = 32768 + (wc >> 1) * 8192 + ((wc & 1) * 64 + l31) * 64;
  int s0 = (((0 + hi5) ^ lkey)) << 3;
  int s1 = (((2 + hi5) ^ lkey)) << 3;
  int s2 = (((4 + hi5) ^ lkey)) << 3;
  int s3 = (((6 + hi5) ^ lkey)) << 3;

  bf16x8 fA[8], fB0[4], fB1[4];
  f32x16 acc[4][2] = {};

  // prologue: tile0 all 4 halves + tile1 {B0,A0}; vmcnt(4) -> tile0 landed
  stage_half(sm, gBs,               32768,         w);
  stage_half(sm, gAs,               0,             w);
  stage_half(sm, gBs + 128L * GK,   32768 + 8192,  w);
  stage_half(sm, gAs + 128L * GK,   8192,          w);
  stage_half(sm, gBs + 64,          32768 + 16384, w);
  stage_half(sm, gAs + 64,          16384,         w);
  VMCNT4();
  BARRIER();

  for (int i = 0; i < NKT / 2 - 1; ++i)
    kiter<true>(sm, i, w, gAs, gBs, Ab0, Bb0, s0, s1, s2, s3, fA, fB0, fB1, acc);
  kiter<false>(sm, NKT / 2 - 1, w, gAs, gBs, Ab0, Bb0, s0, s1, s2, s3, fA, fB0, fB1, acc);

  // ================= fused stage-2 epilogue (wave-local) =================
  // Wave (wr,wc) owns lat rows [wr*128,+128) x cols [wc*64,+64) = group tn*4+wc.
  // 32x32 C/D map (verified R3/m74/m101): col = l31, row = (r&3) + 8*(r>>2) + 4*hi5
  int g_abs = tn * 4 + wc;
#pragma unroll
  for (int mt = 0; mt < 4; ++mt)
#pragma unroll
    for (int nt = 0; nt < 2; ++nt) {
      int rbase = wr * 128 + mt * 32 + hi5 * 4;
      int cl = wc * 64 + nt * 32 + l31;
#pragma unroll
      for (int r = 0; r < 16; ++r) {
        int rl = rbase + (r & 3) + 8 * (r >> 2);
        sm[rl * 260 + cl] = f2bf(acc[mt][nt][r]);
      }
    }
  // per-wave ds_write -> ds_read ordering enforced by compiler lgkmcnt tracking
  const u16* Ug = Ubf + g_abs * 8192;        // [128][64] bf16, K-contiguous
#pragma unroll
  for (int mh = 0; mh < 2; ++mh) {
    bf16x8 fL[8];
#pragma unroll
    for (int ms = 0; ms < 4; ++ms) {
      int rl = wr * 128 + mh * 64 + ms * 16 + lo;
#pragma unroll
      for (int ks = 0; ks < 2; ++ks)
        fL[ms * 2 + ks] = *(const bf16x8*)(sm + rl * 260 + wc * 64 + ks * 32 + hi * 8);
    }
#pragma unroll
    for (int nf = 0; nf < 8; ++nf) {
      int d = nf * 16 + lo;
      bf16x8 u0 = *(const bf16x8*)(Ug + d * 64 + hi * 8);
      bf16x8 u1 = *(const bf16x8*)(Ug + d * 64 + 32 + hi * 8);
      float bias = Ubias[g_abs * 128 + d];
#pragma unroll
      for (int ms = 0; ms < 4; ++ms) {
        f32x4 o = {};
        o = __builtin_amdgcn_mfma_f32_16x16x32_bf16(fL[ms * 2],     u0, o, 0, 0, 0);
        o = __builtin_amdgcn_mfma_f32_16x16x32_bf16(fL[ms * 2 + 1], u1, o, 0, 0, 0);
        long row = (long)tm * 256 + wr * 128 + mh * 64 + ms * 16 + hi * 4;
        int col = g_abs * 128 + d;
#pragma unroll
        for (int j = 0; j < 4; ++j)
          out[(row + j) * 4096 + col] = o[j] + bias;
      }
    }
  }
}

// ============ Fallback (small ws): 128x128 m97-style, A converted in-kernel ============
__global__ __launch_bounds__(256) void gemm1_f32(const float* __restrict__ fAp,
                                                 const u16* __restrict__ B,
                                                 u16* __restrict__ Cl) {
  constexpr int K = 4096;
  __shared__ u16 sA[128 * 32];
  __shared__ u16 sB[128 * 32];
  int bid = blockIdx.x;
  int swz = (bid & 7) * 256 + (bid >> 3);
  int tn = swz & 15;
  int tm = swz >> 4;
  int t = threadIdx.x;
  int w = t >> 6, l = t & 63;
  int wr = w >> 1, wc = w & 1;
  int lo = l & 15, hi = l >> 4;
  const int rS = w * 32 + (l >> 2);
  const int kS = (l & 3) * 8;
  const u16* gB = B + (long)(tn * 128 + rS) * K + kS;
  u16* lB = &sB[w * 1024];
  int fr = t >> 1, fk = (t & 1) * 16;

  f32x4 acc[4][4] = {};
  for (int k0 = 0; k0 < K; k0 += 32) {
    const float* src = fAp + (long)(tm * 128 + fr) * K + k0 + fk;
    float4 x = *(const float4*)(src);
    float4 y = *(const float4*)(src + 4);
    float4 z = *(const float4*)(src + 8);
    float4 q = *(const float4*)(src + 12);
    u16x8 o1, o2;
    o1[0] = f2bf(x.x); o1[1] = f2bf(x.y); o1[2] = f2bf(x.z); o1[3] = f2bf(x.w);
    o1[4] = f2bf(y.x); o1[5] = f2bf(y.y); o1[6] = f2bf(y.z); o1[7] = f2bf(y.w);
    o2[0] = f2bf(z.x); o2[1] = f2bf(z.y); o2[2] = f2bf(z.z); o2[3] = f2bf(z.w);
    o2[4] = f2bf(q.x); o2[5] = f2bf(q.y); o2[6] = f2bf(q.z); o2[7] = f2bf(q.w);
    *(u16x8*)&sA[fr * 32 + fk] = o1;
    *(u16x8*)&sA[fr * 32 + fk + 8] = o2;
    GLOAD_LDS16(gB, lB);
    GLOAD_LDS16(gB + 16 * K, lB + 512);
    gB += 32;
    __syncthreads();
    bf16x8 af[4], bfr[4];
#pragma unroll
    for (int m = 0; m < 4; ++m)
      af[m] = *(const bf16x8*)&sA[(wr * 64 + m * 16 + lo) * 32 + hi * 8];
#pragma unroll
    for (int n = 0; n < 4; ++n)
      bfr[n] = *(const bf16x8*)&sB[(wc * 64 + n * 16 + lo) * 32 + hi * 8];
#pragma unroll
    for (int m = 0; m < 4; ++m)
#pragma unroll
      for (int n = 0; n < 4; ++n)
        acc[m][n] = __builtin_amdgcn_mfma_f32_16x16x32_bf16(af[m], bfr[n], acc[m][n], 0, 0, 0);
    __syncthreads();
  }
#pragma unroll
  for (int m = 0; m < 4; ++m)
#pragma unroll
    for (int n = 0; n < 4; ++n) {
      int col = tn * 128 + wc * 64 + n * 16 + lo;
      int row = tm * 128 + wr * 64 + m * 16 + hi * 4;
#pragma unroll
      for (int j = 0; j < 4; ++j)
        Cl[(long)(row + j) * 2048 + col] = f2bf(acc[m][n][j]);
    }
}

// ---------------- Fallback stage 2 ----------------
__global__ __launch_bounds__(256) void stage2(const u16* __restrict__ L,
                                              const u16* __restrict__ U,
                                              const float* __restrict__ Ub,
                                              float* __restrict__ out) {
  int tm = blockIdx.x, g = blockIdx.y;
  int t = threadIdx.x, w = t >> 6, l = t & 63;
  int lo = l & 15, hi = l >> 4;
  const u16* Lb = L + (long)(tm * 128 + w * 32) * 2048 + g * 64;
  const u16* Ug = U + g * 8192;
  f32x4 acc[2][8] = {};
#pragma unroll
  for (int ks = 0; ks < 2; ++ks) {
    int ek = ks * 32 + hi * 8;
    bf16x8 a0 = *(const bf16x8*)(Lb + (long)lo * 2048 + ek);
    bf16x8 a1 = *(const bf16x8*)(Lb + (long)(lo + 16) * 2048 + ek);
#pragma unroll
    for (int n = 0; n < 8; ++n) {
      bf16x8 bv = *(const bf16x8*)(Ug + (n * 16 + lo) * 64 + ek);
      acc[0][n] = __builtin_amdgcn_mfma_f32_16x16x32_bf16(a0, bv, acc[0][n], 0, 0, 0);
      acc[1][n] = __builtin_amdgcn_mfma_f32_16x16x32_bf16(a1, bv, acc[1][n], 0, 0, 0);
    }
  }
#pragma unroll
  for (int n = 0; n < 8; ++n) {
    int col = n * 16 + lo;
    float bias = Ub[g * 128 + col];
#pragma unroll
    for (int m = 0; m < 2; ++m) {
      int row = tm * 128 + w * 32 + m * 16 + hi * 4;
#pragma unroll
      for (int j = 0; j < 4; ++j)
        out[(long)(row + j) * 4096 + g * 128 + col] = acc[m][n][j] + bias;
    }
  }
}

__global__ __launch_bounds__(256) void cvt_f32_bf16(const float* __restrict__ in,
                                                    u16* __restrict__ out, long n8) {
  long i = (long)blockIdx.x * blockDim.x + threadIdx.x;
  long stride = (long)gridDim.x * blockDim.x;
  for (; i < n8; i += stride) {
    const float4* p = (const float4*)(in + i * 8);
    float4 a = p[0], b = p[1];
    u16x8 o;
    o[0] = f2bf(a.x); o[1] = f2bf(a.y); o[2] = f2bf(a.z); o[3] = f2bf(a.w);
    o[4] = f2bf(b.x); o[5] = f2bf(b.y); o[6] = f2bf(b.z); o[7] = f2bf(b.w);
    *(u16x8*)(out + i * 8) = o;
  }
}

extern "C" void kernel_launch(void* const* d_in, const int* in_sizes, int n_in,
                              void* d_out, int out_size, void* d_ws, size_t ws_size,
                              hipStream_t stream) {
  const float* H   = (const float*)d_in[0];   // [4,4096,4096]
  const float* VT  = (const float*)d_in[1];   // [2048,4096]
  const float* Uw  = (const float*)d_in[2];   // [32,128,64]
  const float* Ubp = (const float*)d_in[3];   // [32,128]
  float* out = (float*)d_out;                 // [4,4096,4096]
  size_t needFull = (size_t)(MH + MV + MU) * 2;   // ~151.6 MB

  if (ws_size >= needFull) {
    u16* hbf = (u16*)d_ws;
    u16* vbf = hbf + MH;
    u16* ubf = vbf + MV;
    cvt_all<<<2048, 256, 0, stream>>>(H, VT, Uw, hbf);
    gemm256_fused<<<512, 512, 0, stream>>>(hbf, vbf, ubf, Ubp, out);
  } else {
    u16* vbf = (u16*)d_ws;
    u16* ubf = vbf + MV;
    u16* lat = ubf + MU;
    cvt_f32_bf16<<<512, 256, 0, stream>>>(VT, vbf, MV / 8);
    cvt_f32_bf16<<<128, 256, 0, stream>>>(Uw, ubf, MU / 8);
    gemm1_f32<<<2048, 256, 0, stream>>>(H, vbf, lat);
    stage2<<<dim3(128, 32), 256, 0, stream>>>(lat, ubf, Ubp, out);
  }
}

// Round 8
// 348.832 us; speedup vs baseline: 1.6185x; 1.0868x over previous
//
#include <hip/hip_runtime.h>
#include <cstdint>

typedef unsigned short u16;
typedef u16 u16x8 __attribute__((ext_vector_type(8)));
typedef __bf16 bf16x8 __attribute__((ext_vector_type(8)));
typedef float f32x4 __attribute__((ext_vector_type(4)));

#define GLOAD_LDS16(g, l)                                                          \
  __builtin_amdgcn_global_load_lds((const __attribute__((address_space(1))) void*)(g), \
                                   (__attribute__((address_space(3))) void*)(l), 16, 0, 0)

#define BARRIER() do { asm volatile("" ::: "memory");                 \
                       __builtin_amdgcn_sched_barrier(0);             \
                       __builtin_amdgcn_s_barrier();                  \
                       __builtin_amdgcn_sched_barrier(0);             \
                       asm volatile("" ::: "memory"); } while (0)
#define VMCNT4() asm volatile("s_waitcnt vmcnt(4)" ::: "memory")
#define VMCNT0() asm volatile("s_waitcnt vmcnt(0)" ::: "memory")
#define LGKM8()  asm volatile("s_waitcnt lgkmcnt(8)" ::: "memory")

__device__ __forceinline__ u16 f2bf(float f) {
  union { float f; uint32_t u; } v; v.f = f;
  uint32_t u = v.u;
  return (u16)((u + 0x7fffu + ((u >> 16) & 1u)) >> 16);  // RNE
}

constexpr long MH = 67108864L;    // 16384*4096
constexpr long MV = 8388608L;     // 2048*4096
constexpr long MU = 262144L;      // 32*128*64

// ---------------- single f32 -> bf16 pass over {H, VT, U} (contiguous dst) ----------------
__global__ __launch_bounds__(256) void cvt_all(const float* __restrict__ H,
                                               const float* __restrict__ VT,
                                               const float* __restrict__ Uw,
                                               u16* __restrict__ dst) {
  const long n8 = (MH + MV + MU) / 8;
  long i = (long)blockIdx.x * blockDim.x + threadIdx.x;
  long stride = (long)gridDim.x * blockDim.x;
  for (; i < n8; i += stride) {
    long j = i * 8;
    const float* src;
    if (j < MH)            src = H + j;
    else if (j < MH + MV)  src = VT + (j - MH);
    else                   src = Uw + (j - MH - MV);
    const float4* p = (const float4*)src;
    float4 a = p[0], b = p[1];
    u16x8 o;
    o[0] = f2bf(a.x); o[1] = f2bf(a.y); o[2] = f2bf(a.z); o[3] = f2bf(a.w);
    o[4] = f2bf(b.x); o[5] = f2bf(b.y); o[6] = f2bf(b.z); o[7] = f2bf(b.w);
    *(u16x8*)(dst + j) = o;
  }
}

// ============ Fused: latents = H @ VT^T (256x256, BK=64, 8-phase, 16x16x32) + U proj ============
constexpr int GK = 4096;
constexpr int NKT = GK / 64;   // 64 K-tiles

__device__ __forceinline__ void stage_half(u16* sm, const u16* g, int ldsbase, int w) {
  u16* l0 = sm + ldsbase + w * 1024;
  GLOAD_LDS16(g, l0);
  GLOAD_LDS16(g + 8 * GK, l0 + 512);
}

__device__ __forceinline__ void readA(const u16* sm, int base, int msub, bf16x8* fA) {
#pragma unroll
  for (int mf = 0; mf < 4; ++mf) {
    int idx = base + (msub * 64 + mf * 16) * 64;
    fA[mf * 2]     = *(const bf16x8*)(sm + idx);
    fA[mf * 2 + 1] = *(const bf16x8*)(sm + (idx ^ 32));   // ks=1: k-slot +4 (XOR bit5)
  }
}

__device__ __forceinline__ void readB(const u16* sm, int base, int qn, bf16x8* fB) {
#pragma unroll
  for (int nf = 0; nf < 2; ++nf) {
    int idx = base + (qn * 32 + nf * 16) * 64;
    fB[nf * 2]     = *(const bf16x8*)(sm + idx);
    fB[nf * 2 + 1] = *(const bf16x8*)(sm + (idx ^ 32));
  }
}

__device__ __forceinline__ void mfma8(const bf16x8* fA, const bf16x8* fB,
                                      f32x4 (*acc)[4], int mbase, int nbase) {
  __builtin_amdgcn_s_setprio(1);
#pragma unroll
  for (int mf = 0; mf < 4; ++mf)
#pragma unroll
    for (int nf = 0; nf < 2; ++nf) {
      acc[mbase + mf][nbase + nf] = __builtin_amdgcn_mfma_f32_16x16x32_bf16(
          fA[mf * 2], fB[nf * 2], acc[mbase + mf][nbase + nf], 0, 0, 0);
      acc[mbase + mf][nbase + nf] = __builtin_amdgcn_mfma_f32_16x16x32_bf16(
          fA[mf * 2 + 1], fB[nf * 2 + 1], acc[mbase + mf][nbase + nf], 0, 0, 0);
    }
  __builtin_amdgcn_s_setprio(0);
}

// One iteration = 2 K-tiles (2i -> buf0, 2i+1 -> buf1), 8 phases (ledger audited R4).
// R8 tweaks vs R5: (a) readB before readA in the 12-read phases; (b) lgkmcnt(8)
// pre-barrier there. Buffers/vmcnt/barrier structure byte-identical to R5.
template <bool MORE>
__device__ __forceinline__ void kiter(u16* sm, int i, int w,
                                      const u16* gAs, const u16* gBs,
                                      int Ab0, int Bb0, bf16x8* fA, bf16x8* fB0,
                                      bf16x8* fB1, f32x4 (*acc)[4]) {
  const long dOdd = (long)(2 * i + 1) * 64;
  const long dE2  = (long)(2 * i + 2) * 64;
  const long dO3  = (long)(2 * i + 3) * 64;
  const long hOff = 128L * GK;

  // ph1: read B(n0) then A(m0) from buf0; stage B1(2i+1)->buf1; partial lgkm drain
  readB(sm, Bb0, 0, fB0);
  readA(sm, Ab0, 0, fA);
  stage_half(sm, gBs + hOff + dOdd, 32768 + 24576, w);
  LGKM8();
  BARRIER();
  mfma8(fA, fB0, acc, 0, 0);
  BARRIER();
  // ph2: read B(n1) buf0; stage A1(2i+1)->buf1; MFMA q(m0,n1)
  readB(sm, Bb0, 1, fB1);
  stage_half(sm, gAs + hOff + dOdd, 24576, w);
  BARRIER();
  mfma8(fA, fB1, acc, 0, 2);
  BARRIER();
  // ph3: read A(m1) buf0; stage B0(2i+2)->buf0 (dead since ph2); MFMA q(m1,n1)
  readA(sm, Ab0, 1, fA);
  if constexpr (MORE) stage_half(sm, gBs + dE2, 32768, w);
  BARRIER();
  mfma8(fA, fB1, acc, 4, 2);
  BARRIER();
  // ph4: stage A0(2i+2)->buf0 (dead since ph3); counted vmcnt; MFMA q(m1,n0)
  if constexpr (MORE) stage_half(sm, gAs + dE2, 0, w);
  if constexpr (MORE) VMCNT4(); else VMCNT0();
  BARRIER();
  mfma8(fA, fB0, acc, 4, 0);
  BARRIER();
  // ph5: read B(n0) then A(m0) from buf1; stage B1(2i+2)->buf0; partial lgkm drain
  readB(sm, Bb0 + 16384, 0, fB0);
  readA(sm, Ab0 + 16384, 0, fA);
  if constexpr (MORE) stage_half(sm, gBs + hOff + dE2, 32768 + 8192, w);
  LGKM8();
  BARRIER();
  mfma8(fA, fB0, acc, 0, 0);
  BARRIER();
  // ph6: read B(n1) buf1; stage A1(2i+2)->buf0
  readB(sm, Bb0 + 16384, 1, fB1);
  if constexpr (MORE) stage_half(sm, gAs + hOff + dE2, 8192, w);
  BARRIER();
  mfma8(fA, fB1, acc, 0, 2);
  BARRIER();
  // ph7: read A(m1) buf1; stage B0(2i+3)->buf1 (dead since ph6)
  readA(sm, Ab0 + 16384, 1, fA);
  if constexpr (MORE) stage_half(sm, gBs + dO3, 32768 + 16384, w);
  BARRIER();
  mfma8(fA, fB1, acc, 4, 2);
  BARRIER();
  // ph8: stage A0(2i+3)->buf1 (dead since ph7); counted vmcnt; MFMA
  if constexpr (MORE) stage_half(sm, gAs + dO3, 16384, w);
  if constexpr (MORE) VMCNT4(); else VMCNT0();
  BARRIER();
  mfma8(fA, fB0, acc, 4, 0);
  BARRIER();
}

__global__ __launch_bounds__(512, 2) void gemm256_fused(const u16* __restrict__ A,
                                                        const u16* __restrict__ B,
                                                        const u16* __restrict__ Ubf,
                                                        const float* __restrict__ Ubias,
                                                        float* __restrict__ out) {
  // LDS: K-loop ring uses [0, 65536); epilogue lat tile [256][260] uses [0, 66560)
  __shared__ u16 sm[66560];
  int bid = blockIdx.x;               // 512 blocks, 512 % 8 == 0 -> bijective XCD swizzle
  int swz = (bid & 7) * 64 + (bid >> 3);
  int tn = swz & 7;
  int tm = swz >> 3;
  int t0 = threadIdx.x;
  int w = t0 >> 6, l = t0 & 63;
  int wr = w >> 2, wc = w & 3;        // 2 M-waves x 4 N-waves; per-wave 128x64 latents
  int lo = l & 15, hi = l >> 4;

  // staging source (pre-swizzled: LDS slot s of row r holds global k-slot s ^ (r&7))
  int lr = l >> 3;
  int sslot = (l & 7) ^ lr;
  const u16* gAs = A + (long)(tm * 256 + w * 16 + lr) * GK + sslot * 8;
  const u16* gBs = B + (long)(tn * 256 + w * 16 + lr) * GK + sslot * 8;

  // ds_read bases (u16): row-in-half = <sub>*16 + lo, 64 u16/row; slot = kslot ^ (lo&7)
  int slotbase = (hi ^ (lo & 7)) * 8;
  int Ab0 = wr * 8192 + lo * 64 + slotbase;
  int Bb0 = 32768 + (wc >> 1) * 8192 + ((wc & 1) * 64 + lo) * 64 + slotbase;

  bf16x8 fA[8], fB0[4], fB1[4];
  f32x4 acc[8][4] = {};

  // prologue: tile0 all 4 halves + tile1 {B0,A0}; vmcnt(4) -> tile0 landed
  stage_half(sm, gBs,               32768,         w);
  stage_half(sm, gAs,               0,             w);
  stage_half(sm, gBs + 128L * GK,   32768 + 8192,  w);
  stage_half(sm, gAs + 128L * GK,   8192,          w);
  stage_half(sm, gBs + 64,          32768 + 16384, w);
  stage_half(sm, gAs + 64,          16384,         w);
  VMCNT4();
  BARRIER();

  for (int i = 0; i < NKT / 2 - 1; ++i)
    kiter<true>(sm, i, w, gAs, gBs, Ab0, Bb0, fA, fB0, fB1, acc);
  kiter<false>(sm, NKT / 2 - 1, w, gAs, gBs, Ab0, Bb0, fA, fB0, fB1, acc);

  // ================= fused stage-2 epilogue (wave-local) =================
  // Wave (wr,wc) owns lat rows [wr*128,+128) x cols [wc*64,+64) = group tn*4+wc.
  int g_abs = tn * 4 + wc;
#pragma unroll
  for (int mq = 0; mq < 8; ++mq)
#pragma unroll
    for (int n = 0; n < 4; ++n) {
      int rl = wr * 128 + mq * 16 + hi * 4;
      int cl = wc * 64 + n * 16 + lo;
#pragma unroll
      for (int j = 0; j < 4; ++j)
        sm[(rl + j) * 260 + cl] = f2bf(acc[mq][n][j]);
    }
  // per-wave ds_write -> ds_read ordering enforced by compiler lgkmcnt tracking
  const u16* Ug = Ubf + g_abs * 8192;        // [128][64] bf16, K-contiguous
#pragma unroll
  for (int mh = 0; mh < 2; ++mh) {
    bf16x8 fL[8];
#pragma unroll
    for (int ms = 0; ms < 4; ++ms) {
      int rl = wr * 128 + mh * 64 + ms * 16 + lo;
#pragma unroll
      for (int ks = 0; ks < 2; ++ks)
        fL[ms * 2 + ks] = *(const bf16x8*)(sm + rl * 260 + wc * 64 + ks * 32 + hi * 8);
    }
#pragma unroll
    for (int nf = 0; nf < 8; ++nf) {
      int d = nf * 16 + lo;
      bf16x8 u0 = *(const bf16x8*)(Ug + d * 64 + hi * 8);
      bf16x8 u1 = *(const bf16x8*)(Ug + d * 64 + 32 + hi * 8);
      float bias = Ubias[g_abs * 128 + d];
#pragma unroll
      for (int ms = 0; ms < 4; ++ms) {
        f32x4 o = {};
        o = __builtin_amdgcn_mfma_f32_16x16x32_bf16(fL[ms * 2],     u0, o, 0, 0, 0);
        o = __builtin_amdgcn_mfma_f32_16x16x32_bf16(fL[ms * 2 + 1], u1, o, 0, 0, 0);
        long row = (long)tm * 256 + wr * 128 + mh * 64 + ms * 16 + hi * 4;
        int col = g_abs * 128 + d;
#pragma unroll
        for (int j = 0; j < 4; ++j)
          out[(row + j) * 4096 + col] = o[j] + bias;
      }
    }
  }
}

// ============ Fallback (small ws): 128x128 m97-style, A converted in-kernel ============
__global__ __launch_bounds__(256) void gemm1_f32(const float* __restrict__ fAp,
                                                 const u16* __restrict__ B,
                                                 u16* __restrict__ Cl) {
  constexpr int K = 4096;
  __shared__ u16 sA[128 * 32];
  __shared__ u16 sB[128 * 32];
  int bid = blockIdx.x;
  int swz = (bid & 7) * 256 + (bid >> 3);
  int tn = swz & 15;
  int tm = swz >> 4;
  int t = threadIdx.x;
  int w = t >> 6, l = t & 63;
  int wr = w >> 1, wc = w & 1;
  int lo = l & 15, hi = l >> 4;
  const int rS = w * 32 + (l >> 2);
  const int kS = (l & 3) * 8;
  const u16* gB = B + (long)(tn * 128 + rS) * K + kS;
  u16* lB = &sB[w * 1024];
  int fr = t >> 1, fk = (t & 1) * 16;

  f32x4 acc[4][4] = {};
  for (int k0 = 0; k0 < K; k0 += 32) {
    const float* src = fAp + (long)(tm * 128 + fr) * K + k0 + fk;
    float4 x = *(const float4*)(src);
    float4 y = *(const float4*)(src + 4);
    float4 z = *(const float4*)(src + 8);
    float4 q = *(const float4*)(src + 12);
    u16x8 o1, o2;
    o1[0] = f2bf(x.x); o1[1] = f2bf(x.y); o1[2] = f2bf(x.z); o1[3] = f2bf(x.w);
    o1[4] = f2bf(y.x); o1[5] = f2bf(y.y); o1[6] = f2bf(y.z); o1[7] = f2bf(y.w);
    o2[0] = f2bf(z.x); o2[1] = f2bf(z.y); o2[2] = f2bf(z.z); o2[3] = f2bf(z.w);
    o2[4] = f2bf(q.x); o2[5] = f2bf(q.y); o2[6] = f2bf(q.z); o2[7] = f2bf(q.w);
    *(u16x8*)&sA[fr * 32 + fk] = o1;
    *(u16x8*)&sA[fr * 32 + fk + 8] = o2;
    GLOAD_LDS16(gB, lB);
    GLOAD_LDS16(gB + 16 * K, lB + 512);
    gB += 32;
    __syncthreads();
    bf16x8 af[4], bfr[4];
#pragma unroll
    for (int m = 0; m < 4; ++m)
      af[m] = *(const bf16x8*)&sA[(wr * 64 + m * 16 + lo) * 32 + hi * 8];
#pragma unroll
    for (int n = 0; n < 4; ++n)
      bfr[n] = *(const bf16x8*)&sB[(wc * 64 + n * 16 + lo) * 32 + hi * 8];
#pragma unroll
    for (int m = 0; m < 4; ++m)
#pragma unroll
      for (int n = 0; n < 4; ++n)
        acc[m][n] = __builtin_amdgcn_mfma_f32_16x16x32_bf16(af[m], bfr[n], acc[m][n], 0, 0, 0);
    __syncthreads();
  }
#pragma unroll
  for (int m = 0; m < 4; ++m)
#pragma unroll
    for (int n = 0; n < 4; ++n) {
      int col = tn * 128 + wc * 64 + n * 16 + lo;
      int row = tm * 128 + wr * 64 + m * 16 + hi * 4;
#pragma unroll
      for (int j = 0; j < 4; ++j)
        Cl[(long)(row + j) * 2048 + col] = f2bf(acc[m][n][j]);
    }
}

// ---------------- Fallback stage 2 ----------------
__global__ __launch_bounds__(256) void stage2(const u16* __restrict__ L,
                                              const u16* __restrict__ U,
                                              const float* __restrict__ Ub,
                                              float* __restrict__ out) {
  int tm = blockIdx.x, g = blockIdx.y;
  int t = threadIdx.x, w = t >> 6, l = t & 63;
  int lo = l & 15, hi = l >> 4;
  const u16* Lb = L + (long)(tm * 128 + w * 32) * 2048 + g * 64;
  const u16* Ug = U + g * 8192;
  f32x4 acc[2][8] = {};
#pragma unroll
  for (int ks = 0; ks < 2; ++ks) {
    int ek = ks * 32 + hi * 8;
    bf16x8 a0 = *(const bf16x8*)(Lb + (long)lo * 2048 + ek);
    bf16x8 a1 = *(const bf16x8*)(Lb + (long)(lo + 16) * 2048 + ek);
#pragma unroll
    for (int n = 0; n < 8; ++n) {
      bf16x8 bv = *(const bf16x8*)(Ug + (n * 16 + lo) * 64 + ek);
      acc[0][n] = __builtin_amdgcn_mfma_f32_16x16x32_bf16(a0, bv, acc[0][n], 0, 0, 0);
      acc[1][n] = __builtin_amdgcn_mfma_f32_16x16x32_bf16(a1, bv, acc[1][n], 0, 0, 0);
    }
  }
#pragma unroll
  for (int n = 0; n < 8; ++n) {
    int col = n * 16 + lo;
    float bias = Ub[g * 128 + col];
#pragma unroll
    for (int m = 0; m < 2; ++m) {
      int row = tm * 128 + w * 32 + m * 16 + hi * 4;
#pragma unroll
      for (int j = 0; j < 4; ++j)
        out[(long)(row + j) * 4096 + g * 128 + col] = acc[m][n][j] + bias;
    }
  }
}

__global__ __launch_bounds__(256) void cvt_f32_bf16(const float* __restrict__ in,
                                                    u16* __restrict__ out, long n8) {
  long i = (long)blockIdx.x * blockDim.x + threadIdx.x;
  long stride = (long)gridDim.x * blockDim.x;
  for (; i < n8; i += stride) {
    const float4* p = (const float4*)(in + i * 8);
    float4 a = p[0], b = p[1];
    u16x8 o;
    o[0] = f2bf(a.x); o[1] = f2bf(a.y); o[2] = f2bf(a.z); o[3] = f2bf(a.w);
    o[4] = f2bf(b.x); o[5] = f2bf(b.y); o[6] = f2bf(b.z); o[7] = f2bf(b.w);
    *(u16x8*)(out + i * 8) = o;
  }
}

extern "C" void kernel_launch(void* const* d_in, const int* in_sizes, int n_in,
                              void* d_out, int out_size, void* d_ws, size_t ws_size,
                              hipStream_t stream) {
  const float* H   = (const float*)d_in[0];   // [4,4096,4096]
  const float* VT  = (const float*)d_in[1];   // [2048,4096]
  const float* Uw  = (const float*)d_in[2];   // [32,128,64]
  const float* Ubp = (const float*)d_in[3];   // [32,128]
  float* out = (float*)d_out;                 // [4,4096,4096]
  size_t needFull = (size_t)(MH + MV + MU) * 2;   // ~151.6 MB

  if (ws_size >= needFull) {
    u16* hbf = (u16*)d_ws;
    u16* vbf = hbf + MH;
    u16* ubf = vbf + MV;
    cvt_all<<<2048, 256, 0, stream>>>(H, VT, Uw, hbf);
    gemm256_fused<<<512, 512, 0, stream>>>(hbf, vbf, ubf, Ubp, out);
  } else {
    u16* vbf = (u16*)d_ws;
    u16* ubf = vbf + MV;
    u16* lat = ubf + MU;
    cvt_f32_bf16<<<512, 256, 0, stream>>>(VT, vbf, MV / 8);
    cvt_f32_bf16<<<128, 256, 0, stream>>>(Uw, ubf, MU / 8);
    gemm1_f32<<<2048, 256, 0, stream>>>(H, vbf, lat);
    stage2<<<dim3(128, 32), 256, 0, stream>>>(lat, ubf, Ubp, out);
  }
}